// Round 8
// baseline (194.211 us; speedup 1.0000x reference)
//
#include <hip/hip_runtime.h>
#include <hip/hip_bf16.h>

// y(x) = levels[ #{j : b[j] < x} ] where levels = [0, cumsum(scale)] and
// b[j] = cumsum[j] - scale[j]*0.5 (contraction OFF to match the reference's
// mul-then-sub rounding at bucket boundaries). idx via v_cmp + v_addc
// (2 VALU/level); levels[idx] is one LDS gather (mostly same-address
// broadcast -> conflict-free).
//
// Round 8 single-variable probe: per-thread f4 count 4 -> 8 (MLP=8, 128 B
// in flight per thread, 3136 exact blocks). Decides queue-cap vs latency
// hypothesis for the ~62 us / 2.45 TB/s plateau.

typedef float vfloat4 __attribute__((ext_vector_type(4)));

__device__ __forceinline__ unsigned qidx(float x, const float* __restrict__ b) {
    unsigned idx = 0u;
#pragma unroll
    for (int j = 0; j < 15; ++j) {
        idx += (b[j] < x) ? 1u : 0u;   // v_cmp_lt_f32 + v_addc_co_u32
    }
    return idx;
}

__global__ __launch_bounds__(256) void nulsq_quant_kernel(
    const float* __restrict__ x, const float* __restrict__ scale,
    float* __restrict__ y, int n4, int n, int full_blocks) {
#pragma clang fp contract(off)
    __shared__ float levels[16];

    float b[15];
    {
        float c = 0.0f;
#pragma unroll
        for (int j = 0; j < 15; ++j) {
            float s = scale[j];       // uniform broadcast loads, L1-cached
            c = c + s;                // cumsum[j], sequential order == jnp.cumsum
            b[j] = c - s * 0.5f;      // mul then sub, no fma
        }
    }
    if (threadIdx.x == 0) {
        float c = 0.0f;
        levels[0] = 0.0f;
#pragma unroll
        for (int j = 0; j < 15; ++j) {
            c = c + scale[j];
            levels[j + 1] = c;        // identical partial sums as reference cumsum
        }
    }
    __syncthreads();

    const vfloat4* __restrict__ x4 = reinterpret_cast<const vfloat4*>(x);
    vfloat4* __restrict__ y4 = reinterpret_cast<vfloat4*>(y);

    const int bx = (int)blockIdx.x;
    const int base = bx * 2048 + (int)threadIdx.x;   // 256 thr * 8 f4 = 2048 f4/block

    if (bx < full_blocks) {
        // Fast path: 8 unguarded back-to-back global_load_dwordx4 per thread.
        vfloat4 v[8];
#pragma unroll
        for (int k = 0; k < 8; ++k) {
            v[k] = x4[base + k * 256];
        }
#pragma unroll
        for (int k = 0; k < 8; ++k) {
            vfloat4 r;
            r.x = levels[qidx(v[k].x, b)];
            r.y = levels[qidx(v[k].y, b)];
            r.z = levels[qidx(v[k].z, b)];
            r.w = levels[qidx(v[k].w, b)];
            __builtin_nontemporal_store(r, &y4[base + k * 256]);
        }
    } else {
        // Guarded tail path (only the last partial block, if any).
#pragma unroll
        for (int k = 0; k < 8; ++k) {
            int fi = base + k * 256;
            if (fi < n4) {
                vfloat4 v = x4[fi];
                vfloat4 r;
                r.x = levels[qidx(v.x, b)];
                r.y = levels[qidx(v.y, b)];
                r.z = levels[qidx(v.z, b)];
                r.w = levels[qidx(v.w, b)];
                __builtin_nontemporal_store(r, &y4[fi]);
            }
        }
        // Scalar remainder for n % 4 != 0 (not hit for this shape).
        int tail = n - n4 * 4;
        if ((int)threadIdx.x < tail && bx == full_blocks) {
            int i = n4 * 4 + (int)threadIdx.x;
            y[i] = levels[qidx(x[i], b)];
        }
    }
}

extern "C" void kernel_launch(void* const* d_in, const int* in_sizes, int n_in,
                              void* d_out, int out_size, void* d_ws, size_t ws_size,
                              hipStream_t stream) {
    const float* x = (const float*)d_in[0];
    const float* scale = (const float*)d_in[1];
    float* y = (float*)d_out;

    int n = in_sizes[0];
    int n4 = n / 4;

    const int block = 256;
    const int f4_per_block = block * 8;            // 2048
    int full_blocks = n4 / f4_per_block;           // 3136 for this shape
    int grid = (n4 + f4_per_block - 1) / f4_per_block;
    if (n - n4 * 4 > 0 && grid == full_blocks) grid += 1;  // scalar-tail coverage
    if (grid < 1) grid = 1;

    nulsq_quant_kernel<<<grid, block, 0, stream>>>(x, scale, y, n4, n, full_blocks);
}

// Round 9
// 188.425 us; speedup vs baseline: 1.0307x; 1.0307x over previous
//
#include <hip/hip_runtime.h>
#include <hip/hip_bf16.h>

// y(x) = levels[ #{j : b[j] < x} ], levels = [0, cumsum(scale)],
// b[j] = cumsum[j] - scale[j]*0.5 (contraction OFF: matches reference
// mul-then-sub rounding at bucket boundaries; partial sums identical to
// jnp.cumsum sequential order).
//
// Round 9 probe: force-minimal VALU. Inline-asm bucket count: per level
// exactly v_cmp_lt_f32 + v_addc_co_u32 (VOP3, carry-in/out vcc, src1=0
// inline const) = 31 VALU/elem vs ~84 emitted in r6 (measured via VALUBusy).
// Structure held at best-known: MLP=4 unguarded fast path, 6272 blocks,
// nontemporal stores, LDS levels gather (mostly same-address broadcast).

typedef float vfloat4 __attribute__((ext_vector_type(4)));

__device__ __forceinline__ unsigned qidx_asm(float x, const float* __restrict__ b) {
    unsigned idx;
    asm("v_mov_b32 %0, 0\n\t"
        "v_cmp_lt_f32 vcc, %1, %16\n\t"
        "v_addc_co_u32 %0, vcc, %0, 0, vcc\n\t"
        "v_cmp_lt_f32 vcc, %2, %16\n\t"
        "v_addc_co_u32 %0, vcc, %0, 0, vcc\n\t"
        "v_cmp_lt_f32 vcc, %3, %16\n\t"
        "v_addc_co_u32 %0, vcc, %0, 0, vcc\n\t"
        "v_cmp_lt_f32 vcc, %4, %16\n\t"
        "v_addc_co_u32 %0, vcc, %0, 0, vcc\n\t"
        "v_cmp_lt_f32 vcc, %5, %16\n\t"
        "v_addc_co_u32 %0, vcc, %0, 0, vcc\n\t"
        "v_cmp_lt_f32 vcc, %6, %16\n\t"
        "v_addc_co_u32 %0, vcc, %0, 0, vcc\n\t"
        "v_cmp_lt_f32 vcc, %7, %16\n\t"
        "v_addc_co_u32 %0, vcc, %0, 0, vcc\n\t"
        "v_cmp_lt_f32 vcc, %8, %16\n\t"
        "v_addc_co_u32 %0, vcc, %0, 0, vcc\n\t"
        "v_cmp_lt_f32 vcc, %9, %16\n\t"
        "v_addc_co_u32 %0, vcc, %0, 0, vcc\n\t"
        "v_cmp_lt_f32 vcc, %10, %16\n\t"
        "v_addc_co_u32 %0, vcc, %0, 0, vcc\n\t"
        "v_cmp_lt_f32 vcc, %11, %16\n\t"
        "v_addc_co_u32 %0, vcc, %0, 0, vcc\n\t"
        "v_cmp_lt_f32 vcc, %12, %16\n\t"
        "v_addc_co_u32 %0, vcc, %0, 0, vcc\n\t"
        "v_cmp_lt_f32 vcc, %13, %16\n\t"
        "v_addc_co_u32 %0, vcc, %0, 0, vcc\n\t"
        "v_cmp_lt_f32 vcc, %14, %16\n\t"
        "v_addc_co_u32 %0, vcc, %0, 0, vcc\n\t"
        "v_cmp_lt_f32 vcc, %15, %16\n\t"
        "v_addc_co_u32 %0, vcc, %0, 0, vcc"
        : "=&v"(idx)
        : "v"(b[0]), "v"(b[1]), "v"(b[2]), "v"(b[3]), "v"(b[4]),
          "v"(b[5]), "v"(b[6]), "v"(b[7]), "v"(b[8]), "v"(b[9]),
          "v"(b[10]), "v"(b[11]), "v"(b[12]), "v"(b[13]), "v"(b[14]),
          "v"(x)
        : "vcc");
    return idx;
}

__global__ __launch_bounds__(256) void nulsq_quant_kernel(
    const float* __restrict__ x, const float* __restrict__ scale,
    float* __restrict__ y, int n4, int n, int full_blocks) {
#pragma clang fp contract(off)
    __shared__ float levels[16];

    float b[15];
    {
        float c = 0.0f;
#pragma unroll
        for (int j = 0; j < 15; ++j) {
            float s = scale[j];       // uniform broadcast loads
            c = c + s;                // cumsum[j], sequential == jnp.cumsum
            b[j] = c - s * 0.5f;      // mul then sub, no fma
        }
    }
    if (threadIdx.x == 0) {
        float c = 0.0f;
        levels[0] = 0.0f;
#pragma unroll
        for (int j = 0; j < 15; ++j) {
            c = c + scale[j];
            levels[j + 1] = c;        // identical partial sums as reference
        }
    }
    __syncthreads();

    const vfloat4* __restrict__ x4 = reinterpret_cast<const vfloat4*>(x);
    vfloat4* __restrict__ y4 = reinterpret_cast<vfloat4*>(y);

    const int bx = (int)blockIdx.x;
    const int base = bx * 1024 + (int)threadIdx.x;   // 256 thr * 4 f4 = 1024 f4/block

    if (bx < full_blocks) {
        // Fast path: 4 unguarded back-to-back global_load_dwordx4.
        vfloat4 v0 = x4[base];
        vfloat4 v1 = x4[base + 256];
        vfloat4 v2 = x4[base + 512];
        vfloat4 v3 = x4[base + 768];

        vfloat4 r;
        r.x = levels[qidx_asm(v0.x, b)];
        r.y = levels[qidx_asm(v0.y, b)];
        r.z = levels[qidx_asm(v0.z, b)];
        r.w = levels[qidx_asm(v0.w, b)];
        __builtin_nontemporal_store(r, &y4[base]);

        r.x = levels[qidx_asm(v1.x, b)];
        r.y = levels[qidx_asm(v1.y, b)];
        r.z = levels[qidx_asm(v1.z, b)];
        r.w = levels[qidx_asm(v1.w, b)];
        __builtin_nontemporal_store(r, &y4[base + 256]);

        r.x = levels[qidx_asm(v2.x, b)];
        r.y = levels[qidx_asm(v2.y, b)];
        r.z = levels[qidx_asm(v2.z, b)];
        r.w = levels[qidx_asm(v2.w, b)];
        __builtin_nontemporal_store(r, &y4[base + 512]);

        r.x = levels[qidx_asm(v3.x, b)];
        r.y = levels[qidx_asm(v3.y, b)];
        r.z = levels[qidx_asm(v3.z, b)];
        r.w = levels[qidx_asm(v3.w, b)];
        __builtin_nontemporal_store(r, &y4[base + 768]);
    } else {
        // Guarded tail path (only the last partial block, if any).
#pragma unroll
        for (int k = 0; k < 4; ++k) {
            int fi = base + k * 256;
            if (fi < n4) {
                vfloat4 v = x4[fi];
                vfloat4 r;
                r.x = levels[qidx_asm(v.x, b)];
                r.y = levels[qidx_asm(v.y, b)];
                r.z = levels[qidx_asm(v.z, b)];
                r.w = levels[qidx_asm(v.w, b)];
                __builtin_nontemporal_store(r, &y4[fi]);
            }
        }
        // Scalar remainder for n % 4 != 0 (not hit for this shape).
        int tail = n - n4 * 4;
        if ((int)threadIdx.x < tail && bx == full_blocks) {
            int i = n4 * 4 + (int)threadIdx.x;
            y[i] = levels[qidx_asm(x[i], b)];
        }
    }
}

extern "C" void kernel_launch(void* const* d_in, const int* in_sizes, int n_in,
                              void* d_out, int out_size, void* d_ws, size_t ws_size,
                              hipStream_t stream) {
    const float* x = (const float*)d_in[0];
    const float* scale = (const float*)d_in[1];
    float* y = (float*)d_out;

    int n = in_sizes[0];
    int n4 = n / 4;

    const int block = 256;
    const int f4_per_block = block * 4;            // 1024
    int full_blocks = n4 / f4_per_block;           // 6272 for this shape
    int grid = (n4 + f4_per_block - 1) / f4_per_block;
    if (n - n4 * 4 > 0 && grid == full_blocks) grid += 1;  // scalar-tail coverage
    if (grid < 1) grid = 1;

    nulsq_quant_kernel<<<grid, block, 0, stream>>>(x, scale, y, n4, n, full_blocks);
}